// Round 11
// baseline (341.549 us; speedup 1.0000x reference)
//
#include <hip/hip_runtime.h>
#include <hip/hip_bf16.h>
#include <math.h>
#include <stdint.h>

#define BATCH 2
#define NH 12
#define SEQ 2048
#define HD 64
#define TQ 64
#define TK 64
#define NHEADS (BATCH*NH)
#define NIT (SEQ / TK)
#define NBLK (NHEADS * (SEQ / TQ))   // 768
#define HTILES (NIT / 2)             // 16 KV tiles per half

typedef short bf16x8 __attribute__((ext_vector_type(8)));
typedef float f32x4 __attribute__((ext_vector_type(4)));
typedef float f32x16 __attribute__((ext_vector_type(16)));
typedef unsigned short us4_t __attribute__((ext_vector_type(4)));
typedef unsigned short us8_t __attribute__((ext_vector_type(8)));
typedef unsigned int u32x4 __attribute__((ext_vector_type(4)));

#if __has_builtin(__builtin_amdgcn_exp2f)
#define EXP2F(x) __builtin_amdgcn_exp2f(x)
#else
#define EXP2F(x) exp2f(x)
#endif

static __device__ __forceinline__ unsigned short f2bf(float f) {
    unsigned int u = __float_as_uint(f);
    u += 0x7fffu + ((u >> 16) & 1u);   // RTNE
    return (unsigned short)(u >> 16);
}

static __device__ __forceinline__ unsigned int pack2bf(float a, float b) {
    __hip_bfloat162 v = __float22bfloat162_rn(float2{a, b});
    return *(unsigned int*)&v;          // low short = a
}

// Conflict-free 64x64-bf16 tile layout (staging only): 32 row-pairs x 256B,
// 16 positions of 16B, pos = ((r&1)*8 | c) ^ ((r>>1)&15).
static __device__ __forceinline__ int tile_off(int r, int c) {   // shorts, c 0..7
    int rp  = r >> 1;
    int pos = (((r & 1) << 3) | c) ^ (rp & 15);
    return rp * 128 + pos * 8;
}

// ---- pre-pass (R16 version): K and V -> FRAGMENT-LINEAR bf16 workspaces.
// Kb:  per (bh,tile,nt): 2048 shorts = [s 0..3][lane 0..63] of 8 bf16 each.
// Vtb: per (bh,tile): 4096 shorts, fragment index o8 = cg*128 + hi*64 + d.
// V fragment writes are TID-LINEAR (dense 4KB per pass); T gather reads one
// contiguous 128B row per j (conflict-free broadcast row-read).
__global__ __launch_bounds__(256)
void prep_kv(const float* __restrict__ K, const float* __restrict__ V,
             unsigned short* __restrict__ Kb, unsigned short* __restrict__ Vtb) {
    __shared__ unsigned short T[64][66];       // V transpose staging
    __shared__ unsigned short KT[4096];        // K tile in tile_off layout (8 KB)
    const int bh   = blockIdx.x >> 5;
    const int tile = blockIdx.x & 31;
    const int s0   = tile * 64;
    const int tid  = threadIdx.x;
    const size_t off = ((size_t)bh * SEQ + s0) * HD;

    #pragma unroll
    for (int u = 0; u < 4; ++u) {              // K: dense f32 -> KT (tile_off)
        int idx = u * 1024 + tid * 4;
        int r = idx >> 6, col = idx & 63;
        float4 a = *(const float4*)&K[off + idx];
        uint2 pk = { pack2bf(a.x, a.y), pack2bf(a.z, a.w) };
        *(uint2*)&KT[tile_off(r, col >> 3) + (col & 7)] = pk;
    }
    #pragma unroll
    for (int u = 0; u < 4; ++u) {              // V: dense loads -> padded LDS
        int idx = u * 1024 + tid * 4;
        int r = idx >> 6, col = idx & 63;
        float4 a = *(const float4*)&V[off + idx];
        *(unsigned int*)&T[r][col]     = pack2bf(a.x, a.y);
        *(unsigned int*)&T[r][col + 2] = pack2bf(a.z, a.w);
    }
    __syncthreads();

    // K fragment writes: 16B/lane, lane-consecutive -> 1KB per wave-store.
    {
        const int lane = tid & 63, s = tid >> 6;
        unsigned short* KbT = Kb + ((size_t)(bh * 32 + tile) * 2) * 2048;
        #pragma unroll
        for (int nt = 0; nt < 2; ++nt) {
            bf16x8 f = *(const bf16x8*)&KT[tile_off(nt * 32 + (lane & 31),
                                                    s * 2 + (lane >> 5))];
            *(bf16x8*)&KbT[(size_t)nt * 2048 + s * 512 + lane * 8] = f;
        }
    }
    // V fragment writes: tid-linear fragment index -> dense contiguous stores.
    {
        unsigned short* VbT = Vtb + (size_t)(bh * 32 + tile) * 4096;
        #pragma unroll
        for (int h = 0; h < 2; ++h) {
            int o8 = tid + 256 * h;            // fragment index 0..511
            int d  = o8 & 63;                  // V^T row (d-index)
            int hi = (o8 >> 6) & 1;
            int cg = o8 >> 7;                  // (nt*2+ks), 0..3
            int g  = ((cg >> 1) << 2) | ((cg & 1) << 1) | hi;
            us8_t r8;
            #pragma unroll
            for (int j = 0; j < 8; ++j) {
                // pi: swap bits 2,3 of the 64-local column index (g*8 + j)
                int src = ((g >> 1) << 4) + ((j >> 2) << 3) + ((g & 1) << 2) + (j & 3);
                r8[j] = T[src][d];
            }
            *(us8_t*)&VbT[o8 * 8] = r8;
        }
    }
}

// ---------------- main flash-attention kernel, KV-SPLIT x2 -------------------
// R17: the loop is latency-bound at 3 blocks/CU (MfmaUtil 17%, VALUBusy 26%,
// nothing saturated) and every scheduling attack moved it +-3us. The untouched
// axis is TLP: grid was always 768 = 3/CU. This softmax has NO running max
// (plain exp2), so partial attention is exactly associative:
// O = (O0+O1)/(l0+l1). Split KV in half -> 1536 blocks = 6/CU = 24 waves/CU
// (VGPR 76 <= 85 cap at launch_bounds(256,6); LDS 16.9KB). Each block runs the
// R15 barrier-free fragment-linear loop (K same-iter FIN-covered, V dist-1 —
// the R16 K-dist-1 variant measured WORSE, reverted) for 16 tiles and writes
// unnormalized partial O + row-sums; reduce_o combines and normalizes.
// Halves interleaved (half = blockIdx&1) so same-(bh,qt) pairs share Q in L2.
__global__ __launch_bounds__(256, 6)
void fa_split(const float* __restrict__ Q,
              const unsigned short* __restrict__ Kb,
              const unsigned short* __restrict__ Vtb,
              float* __restrict__ Opart, float* __restrict__ Lpart, float qs) {
    const int b    = blockIdx.x;
    const int half = b & 1;
    const int bb   = b >> 1;
    const int x  = bb & 7;
    const int t  = bb >> 3;
    const int bh = x + 8 * (t % 3);
    const int qt = t / 3;
    const int q0 = qt * TQ;

    __shared__ __align__(16) unsigned char SH[16896];
    unsigned short* QS = (unsigned short*)SH;              // prologue only
    float* ORed = (float*)SH;                              // 64x64 f32 (epilogue)
    float* Lsum = (float*)(SH + 16384);                    // 64 f32

    const int tid  = threadIdx.x;
    const int w    = tid >> 6;
    const int mt   = w >> 1;
    const int nt   = w & 1;
    const int lane = tid & 63;
    const int l31  = lane & 31;
    const int hi   = lane >> 5;

    const float* Qh = Q + ((size_t)bh * SEQ + q0) * HD;

    // ---- prologue: Q (fp32 -> scaled bf16) -> QS; extract B-fragments ----
    #pragma unroll
    for (int u = 0; u < 4; ++u) {
        int idx = u * 1024 + tid * 4;
        int r = idx >> 6, col = idx & 63;
        float4 a = *(const float4*)&Qh[idx];
        uint2 pk = { pack2bf(a.x * qs, a.y * qs), pack2bf(a.z * qs, a.w * qs) };
        *(uint2*)&QS[tile_off(r, col >> 3) + (col & 7)] = pk;
    }
    __syncthreads();
    bf16x8 qf[4];
    #pragma unroll
    for (int s = 0; s < 4; ++s)
        qf[s] = *(const bf16x8*)&QS[tile_off(mt * 32 + l31, s * 2 + hi)];
    __syncthreads();   // all waves extracted qf; ORed overlay safe after this

    // ---- per-lane fragment-linear bases, offset to this block's KV half ----
    const unsigned short* kB = Kb  + ((size_t)bh * 32 * 2 + nt) * 2048 + lane * 8
                                   + (size_t)half * HTILES * 4096;
    const unsigned short* vB = Vtb + (size_t)bh * 32 * 4096
                                   + (size_t)(nt * 2) * 1024 + hi * 512 + l31 * 8
                                   + (size_t)half * HTILES * 4096;

    f32x16 o[2];
    o[0] = (f32x16)(0.f);
    o[1] = (f32x16)(0.f);
    float lsum = 0.f;

    // deferred finish: exp2 + pack + PV + lsum (register-only)
    auto FIN = [&](const f32x16& sp, const bf16x8 (&vp)[2][2]) {
        float e0[8], e1[8];
        #pragma unroll
        for (int r = 0; r < 8; ++r) e0[r] = EXP2F(sp[r]);
        #pragma unroll
        for (int r = 0; r < 8; ++r) e1[r] = EXP2F(sp[8 + r]);
        union { u32x4 d; bf16x8 h; } pu0, pu1;
        pu0.d = (u32x4){ pack2bf(e0[0], e0[1]), pack2bf(e0[2], e0[3]),
                         pack2bf(e0[4], e0[5]), pack2bf(e0[6], e0[7]) };
        pu1.d = (u32x4){ pack2bf(e1[0], e1[1]), pack2bf(e1[2], e1[3]),
                         pack2bf(e1[4], e1[5]), pack2bf(e1[6], e1[7]) };
        bf16x8 pf0 = pu0.h, pf1 = pu1.h;
        __builtin_amdgcn_s_setprio(1);
        o[0] = __builtin_amdgcn_mfma_f32_32x32x16_bf16(pf0, vp[0][0], o[0], 0, 0, 0);
        o[1] = __builtin_amdgcn_mfma_f32_32x32x16_bf16(pf0, vp[1][0], o[1], 0, 0, 0);
        o[0] = __builtin_amdgcn_mfma_f32_32x32x16_bf16(pf1, vp[0][1], o[0], 0, 0, 0);
        o[1] = __builtin_amdgcn_mfma_f32_32x32x16_bf16(pf1, vp[1][1], o[1], 0, 0, 0);
        __builtin_amdgcn_s_setprio(0);
        float t0 = ((e0[0] + e0[1]) + (e0[2] + e0[3]))
                 + ((e0[4] + e0[5]) + (e0[6] + e0[7]));
        float t1 = ((e1[0] + e1[1]) + (e1[2] + e1[3]))
                 + ((e1[4] + e1[5]) + (e1[6] + e1[7]));
        lsum += t0 + t1;
    };

    // pipeline state
    f32x16 scp;
    bf16x8 vfp[2][2];

    // ---- peeled iteration 0 ----
    {
        bf16x8 kc[4];
        #pragma unroll
        for (int s = 0; s < 4; ++s) kc[s] = *(const bf16x8*)(kB + s * 512);
        #pragma unroll
        for (int dt = 0; dt < 2; ++dt)
            #pragma unroll
            for (int ks = 0; ks < 2; ++ks)
                vfp[dt][ks] = *(const bf16x8*)(vB + ks * 1024 + dt * 256);
        f32x16 sc = (f32x16)(0.f);
        __builtin_amdgcn_s_setprio(1);
        #pragma unroll
        for (int s = 0; s < 4; ++s)
            sc = __builtin_amdgcn_mfma_f32_32x32x16_bf16(kc[s], qf[s], sc, 0, 0, 0);
        __builtin_amdgcn_s_setprio(0);
        scp = sc;
    }

    // ---- main loop (no barriers): iter t = {load V(t),K(t) -> FIN(t-1) ->
    //                                          QK(t) -> rotate} ----
    #pragma unroll 2
    for (int it = 1; it < HTILES; ++it) {
        const unsigned short* kT = kB + (size_t)it * 4096;
        const unsigned short* vT = vB + (size_t)it * 4096;

        bf16x8 vn[2][2];
        #pragma unroll
        for (int dt = 0; dt < 2; ++dt)
            #pragma unroll
            for (int ks = 0; ks < 2; ++ks)
                vn[dt][ks] = *(const bf16x8*)(vT + ks * 1024 + dt * 256);
        bf16x8 kc[4];
        #pragma unroll
        for (int s = 0; s < 4; ++s) kc[s] = *(const bf16x8*)(kT + s * 512);

        FIN(scp, vfp);

        f32x16 scc = (f32x16)(0.f);
        __builtin_amdgcn_s_setprio(1);
        #pragma unroll
        for (int s = 0; s < 4; ++s)
            scc = __builtin_amdgcn_mfma_f32_32x32x16_bf16(kc[s], qf[s], scc, 0, 0, 0);
        __builtin_amdgcn_s_setprio(0);

        scp = scc;
        #pragma unroll
        for (int dt = 0; dt < 2; ++dt)
            #pragma unroll
            for (int ks = 0; ks < 2; ++ks)
                vfp[dt][ks] = vn[dt][ks];
    }

    // ---- tail: finish the last tile ----
    FIN(scp, vfp);

    // ---- epilogue: combine nt partials; write UNNORMALIZED partial O + l ----
    lsum += __shfl_xor(lsum, 32, 64);

    if (nt == 1) {
        if (lane < 32) Lsum[mt * 32 + lane] = lsum;
        #pragma unroll
        for (int dt = 0; dt < 2; ++dt) {
            const int d = dt * 32 + l31;
            #pragma unroll
            for (int g = 0; g < 4; ++g) {
                const int m0 = mt * 32 + 8 * g + 4 * hi;
                const int ph = (m0 >> 2) ^ (d & 15);
                float4 v = { o[dt][4*g+0], o[dt][4*g+1], o[dt][4*g+2], o[dt][4*g+3] };
                *(float4*)&ORed[d * 64 + ph * 4] = v;
            }
        }
    }
    __syncthreads();

    if (nt == 0) {
        float ltot = lsum + Lsum[mt * 32 + l31];
        float* Lp = Lpart + (size_t)half * (NHEADS * SEQ);
        if (lane < 32) Lp[(size_t)bh * SEQ + q0 + mt * 32 + lane] = ltot;
        float* Po = Opart + (size_t)half * ((size_t)NHEADS * SEQ * HD)
                          + ((size_t)bh * SEQ + q0) * HD;
        #pragma unroll
        for (int dt = 0; dt < 2; ++dt) {
            const int d = dt * 32 + l31;
            #pragma unroll
            for (int g = 0; g < 4; ++g) {
                const int m0 = mt * 32 + 8 * g + 4 * hi;
                const int ph = (m0 >> 2) ^ (d & 15);
                float4 part = *(const float4*)&ORed[d * 64 + ph * 4];
                const float* pp = (const float*)&part;
                #pragma unroll
                for (int j = 0; j < 4; ++j)
                    Po[(size_t)(m0 + j) * HD + d] = o[dt][4*g+j] + pp[j];
            }
        }
    }
}

// ---- combine: O = (P0 + P1) / (l0 + l1), float4-vectorized ----
__global__ __launch_bounds__(256)
void reduce_o(const float4* __restrict__ P0, const float4* __restrict__ P1,
              const float* __restrict__ L0, const float* __restrict__ L1,
              float4* __restrict__ O) {
    const int idx = blockIdx.x * 256 + threadIdx.x;   // float4 index
    const int row = idx >> 4;                         // 16 float4 per 64-f32 row
    const float inv = 1.0f / (L0[row] + L1[row]);
    float4 a = P0[idx], bq = P1[idx];
    float4 r = { (a.x + bq.x) * inv, (a.y + bq.y) * inv,
                 (a.z + bq.z) * inv, (a.w + bq.w) * inv };
    O[idx] = r;
}

// ---------------- fallback (no-workspace) kernel ----------------
#define PAD 8
#define LSTR (HD + PAD)

__global__ __launch_bounds__(256)
void fa_fwd_fb(const float* __restrict__ Q, const float* __restrict__ K,
               const float* __restrict__ V, float* __restrict__ O) {
    const int x  = blockIdx.x & 7;
    const int t  = blockIdx.x >> 3;
    const int bh = x + 8 * (t % 3);
    const int qt = t / 3;
    const int q0 = qt * TQ;
    const long base = (long)bh * SEQ * HD;

    __shared__ unsigned short Qs[TQ][LSTR];
    __shared__ unsigned short Ks2[64][LSTR];
    __shared__ unsigned short Vt[HD][64 + PAD];
    __shared__ unsigned short Ps2[4][16][LSTR];

    const int tid  = threadIdx.x;
    const int wave = tid >> 6;
    const int lane = tid & 63;
    const int col  = lane & 15;
    const int quad = lane >> 4;
    const int m0   = wave * 16;

    #pragma unroll
    for (int i = 0; i < 4; ++i) {
        int idx = tid + 256 * i;
        int row = idx >> 4;
        int c4  = (idx & 15) * 4;
        float4 v = *(const float4*)&Q[base + (long)(q0 + row) * HD + c4];
        ushort4 b = { f2bf(v.x), f2bf(v.y), f2bf(v.z), f2bf(v.w) };
        *(ushort4*)&Qs[row][c4] = b;
    }
    __syncthreads();

    bf16x8 aq0 = *(const bf16x8*)&Qs[m0 + col][quad * 8];
    bf16x8 aq1 = *(const bf16x8*)&Qs[m0 + col][32 + quad * 8];

    f32x4 o0 = {0.f,0.f,0.f,0.f}, o1 = o0, o2 = o0, o3 = o0;
    float l[4] = {0.f, 0.f, 0.f, 0.f};
    const float scale = 0.022097086912079608f;

    for (int kv0 = 0; kv0 < SEQ; kv0 += 64) {
        __syncthreads();
        #pragma unroll
        for (int i = 0; i < 4; ++i) {
            int idx = tid + 256 * i;
            int row = idx >> 4;
            int c4  = (idx & 15) * 4;
            float4 kv = *(const float4*)&K[base + (long)(kv0 + row) * HD + c4];
            ushort4 kb = { f2bf(kv.x), f2bf(kv.y), f2bf(kv.z), f2bf(kv.w) };
            *(ushort4*)&Ks2[row][c4] = kb;
            float4 vv = *(const float4*)&V[base + (long)(kv0 + row) * HD + c4];
            Vt[c4 + 0][row] = f2bf(vv.x);
            Vt[c4 + 1][row] = f2bf(vv.y);
            Vt[c4 + 2][row] = f2bf(vv.z);
            Vt[c4 + 3][row] = f2bf(vv.w);
        }
        __syncthreads();

        f32x4 sc[4];
        #pragma unroll
        for (int n = 0; n < 4; ++n) {
            bf16x8 b0 = *(const bf16x8*)&Ks2[n * 16 + col][quad * 8];
            bf16x8 b1 = *(const bf16x8*)&Ks2[n * 16 + col][32 + quad * 8];
            f32x4 acc = {0.f,0.f,0.f,0.f};
            acc = __builtin_amdgcn_mfma_f32_16x16x32_bf16(aq0, b0, acc, 0, 0, 0);
            acc = __builtin_amdgcn_mfma_f32_16x16x32_bf16(aq1, b1, acc, 0, 0, 0);
            sc[n] = acc;
        }

        float tsum[4] = {0.f, 0.f, 0.f, 0.f};
        #pragma unroll
        for (int n = 0; n < 4; ++n) {
            #pragma unroll
            for (int r = 0; r < 4; ++r) {
                float p = __expf(sc[n][r] * scale);
                tsum[r] += p;
                Ps2[wave][quad * 4 + r][n * 16 + col] = f2bf(p);
            }
        }
        #pragma unroll
        for (int off = 1; off < 16; off <<= 1) {
            #pragma unroll
            for (int r = 0; r < 4; ++r) tsum[r] += __shfl_xor(tsum[r], off, 64);
        }
        #pragma unroll
        for (int r = 0; r < 4; ++r) l[r] += tsum[r];

        bf16x8 ap0 = *(const bf16x8*)&Ps2[wave][col][quad * 8];
        bf16x8 ap1 = *(const bf16x8*)&Ps2[wave][col][32 + quad * 8];
        #pragma unroll
        for (int n = 0; n < 4; ++n) {
            bf16x8 b0 = *(const bf16x8*)&Vt[n * 16 + col][quad * 8];
            bf16x8 b1 = *(const bf16x8*)&Vt[n * 16 + col][32 + quad * 8];
            f32x4* op = (n == 0) ? &o0 : (n == 1) ? &o1 : (n == 2) ? &o2 : &o3;
            *op = __builtin_amdgcn_mfma_f32_16x16x32_bf16(ap0, b0, *op, 0, 0, 0);
            *op = __builtin_amdgcn_mfma_f32_16x16x32_bf16(ap1, b1, *op, 0, 0, 0);
        }
    }

    float inv[4];
    #pragma unroll
    for (int r = 0; r < 4; ++r) inv[r] = 1.0f / l[r];
    #pragma unroll
    for (int r = 0; r < 4; ++r) {
        long row = base + (long)(q0 + m0 + quad * 4 + r) * HD;
        O[row +  0 + col] = o0[r] * inv[r];
        O[row + 16 + col] = o1[r] * inv[r];
        O[row + 32 + col] = o2[r] * inv[r];
        O[row + 48 + col] = o3[r] * inv[r];
    }
}

extern "C" void kernel_launch(void* const* d_in, const int* in_sizes, int n_in,
                              void* d_out, int out_size, void* d_ws, size_t ws_size,
                              hipStream_t stream) {
    const float* Q = (const float*)d_in[0];
    const float* K = (const float*)d_in[1];
    const float* V = (const float*)d_in[2];
    float* O = (float*)d_out;

    const size_t tensorElems = (size_t)NHEADS * SEQ * HD;
    const size_t lElems      = (size_t)NHEADS * SEQ;
    // Kb + Vtb (bf16) + 2x partial O (f32) + 2x partial l (f32)
    const size_t need = 2 * tensorElems * sizeof(unsigned short)
                      + 2 * tensorElems * sizeof(float)
                      + 2 * lElems * sizeof(float);

    if (ws_size >= need) {
        unsigned short* Kb  = (unsigned short*)d_ws;
        unsigned short* Vtb = Kb + tensorElems;
        float* Opart = (float*)(Vtb + tensorElems);
        float* Lpart = Opart + 2 * tensorElems;
        const float qs = (float)(1.4426950408889634 / sqrt(2048.0));  // log2e/sqrt(S)
        prep_kv<<<dim3(NHEADS * (SEQ / 64)), dim3(256), 0, stream>>>(K, V, Kb, Vtb);
        fa_split<<<dim3(2 * NBLK), dim3(256), 0, stream>>>(Q, Kb, Vtb, Opart, Lpart, qs);
        reduce_o<<<dim3((unsigned)(tensorElems / 4 / 256)), dim3(256), 0, stream>>>(
            (const float4*)Opart, (const float4*)(Opart + tensorElems),
            Lpart, Lpart + lElems, (float4*)O);
    } else {
        fa_fwd_fb<<<dim3(NHEADS * (SEQ / TQ)), dim3(256), 0, stream>>>(Q, K, V, O);
    }
}

// Round 13
// 114.447 us; speedup vs baseline: 2.9843x; 2.9843x over previous
//
#include <hip/hip_runtime.h>
#include <hip/hip_bf16.h>
#include <math.h>
#include <stdint.h>

#define BATCH 2
#define NH 12
#define SEQ 2048
#define HD 64
#define TQ 64
#define TK 64
#define NHEADS (BATCH*NH)
#define NIT (SEQ / TK)

typedef short bf16x8 __attribute__((ext_vector_type(8)));
typedef float f32x4 __attribute__((ext_vector_type(4)));
typedef float f32x16 __attribute__((ext_vector_type(16)));
typedef unsigned short us4_t __attribute__((ext_vector_type(4)));
typedef unsigned short us8_t __attribute__((ext_vector_type(8)));
typedef unsigned int u32x4 __attribute__((ext_vector_type(4)));

#if __has_builtin(__builtin_amdgcn_exp2f)
#define EXP2F(x) __builtin_amdgcn_exp2f(x)
#else
#define EXP2F(x) exp2f(x)
#endif

static __device__ __forceinline__ unsigned short f2bf(float f) {
    unsigned int u = __float_as_uint(f);
    u += 0x7fffu + ((u >> 16) & 1u);   // RTNE
    return (unsigned short)(u >> 16);
}

static __device__ __forceinline__ unsigned int pack2bf(float a, float b) {
    __hip_bfloat162 v = __float22bfloat162_rn(float2{a, b});
    return *(unsigned int*)&v;          // low short = a
}

static __device__ __forceinline__ void async_cp16(const void* g, void* l) {
    __builtin_amdgcn_global_load_lds(
        (const __attribute__((address_space(1))) void*)g,
        (__attribute__((address_space(3))) void*)(uintptr_t)l,
        16, 0, 0);
}

// Conflict-free 64x64-bf16 tile layout: 32 row-pairs x 256B, 16 positions of
// 16B, pos = ((r&1)*8 | c) ^ ((r>>1)&15).
static __device__ __forceinline__ int tile_off(int r, int c) {   // shorts, c 0..7
    int rp  = r >> 1;
    int pos = (((r & 1) << 3) | c) ^ (rp & 15);
    return rp * 128 + pos * 8;
}

// ---- pre-pass: K -> bf16 (dense), V -> bf16 transposed [bh][d][s'] where
// s' = s with bits 2<->3 swapped inside each 32-block (pi-permutation that
// makes the S^T C-layout register order equal the PV A-operand order).
__global__ __launch_bounds__(256)
void prep_kv(const float* __restrict__ K, const float* __restrict__ V,
             unsigned short* __restrict__ Kb, unsigned short* __restrict__ Vtb) {
    __shared__ unsigned short T[64][66];
    const int bh = blockIdx.x >> 5;
    const int s0 = (blockIdx.x & 31) * 64;
    const int tid = threadIdx.x;
    const size_t off = ((size_t)bh * SEQ + s0) * HD;

    #pragma unroll
    for (int u = 0; u < 4; ++u) {                 // K: dense 16B loads, 8B stores
        int idx = u * 1024 + tid * 4;
        float4 a = *(const float4*)&K[off + idx];
        us4_t r4 = { f2bf(a.x), f2bf(a.y), f2bf(a.z), f2bf(a.w) };
        *(us4_t*)&Kb[off + idx] = r4;
    }
    #pragma unroll
    for (int u = 0; u < 4; ++u) {                 // V: dense loads -> padded LDS
        int idx = u * 1024 + tid * 4;
        int r = idx >> 6, col = idx & 63;
        float4 a = *(const float4*)&V[off + idx];
        *(unsigned int*)&T[r][col]     = pack2bf(a.x, a.y);
        *(unsigned int*)&T[r][col + 2] = pack2bf(a.z, a.w);
    }
    __syncthreads();
    unsigned short* Vdst = Vtb + (size_t)bh * HD * SEQ;
    const int g = tid & 7, dd = tid >> 3;         // dd 0..31
    #pragma unroll
    for (int h = 0; h < 2; ++h) {
        int d = dd + 32 * h;
        us8_t r8;
        #pragma unroll
        for (int j = 0; j < 8; ++j) {
            // pi: swap bits 2,3 of the 64-local column index (g*8 + j)
            int src = ((g >> 1) << 4) + ((j >> 2) << 3) + ((g & 1) << 2) + (j & 3);
            r8[j] = T[src][d];
        }
        *(us8_t*)&Vdst[(size_t)d * SEQ + s0 + g * 8] = r8;
    }
}

// ---------------- main flash-attention kernel (32x32x16 MFMA) ----------------
// R13 structure (session best: 114.985 us). Tri-buffered async K/V staging,
// prefetch distance 2, counted vmcnt(4) (R12 A/B: worth ~20us vs dbuf+drain),
// deferred-PV FIN pipeline placed in the ds_read latency shadow:
//   barrier -> issue ALL 8 ds_reads (kfc[] + vfc[]) -> issue gl_lds prefetch
//   -> FIN(t-1) (register-only, ~300 cyc) -> QK(t) on pre-read fragments.
// Rejected by measurement: dbuf+drain (R12, 60us), barrier-free row-major
// (R11, 98us), K-f32 fusion (R14, 56-61us), K-dist-1 (R16, 56us), grid-barrier
// fusion (R10, 131us+), KV-split@(256,6) (R17, spills, 262us+).
__global__ __launch_bounds__(256, 3)
void fa_main(const float* __restrict__ Q,
             const unsigned short* __restrict__ Kb,
             const unsigned short* __restrict__ Vtb,
             float* __restrict__ O, float qs) {
    const int x  = blockIdx.x & 7;
    const int t  = blockIdx.x >> 3;
    const int bh = x + 8 * (t % 3);
    const int qt = t / 3;
    const int q0 = qt * TQ;

    // 3 buffers x (K 8KB + V 8KB) + Lsum/Linv
    __shared__ __align__(16) unsigned char SH[49664];
    float* Lsum = (float*)(SH + 49152);                    // 64 f32
    float* Linv = (float*)(SH + 49408);                    // 64 f32
    float* ORed = (float*)SH;                              // 64x64 f32 overlay (buf0)
    unsigned short* QS = (unsigned short*)(SH + 32768);    // Q staging (buf2 K half)

    const int tid  = threadIdx.x;
    const int w    = tid >> 6;
    const int mt   = w >> 1;
    const int nt   = w & 1;
    const int lane = tid & 63;
    const int l31  = lane & 31;
    const int hi   = lane >> 5;

    const float*          Qh = Q   + ((size_t)bh * SEQ + q0) * HD;
    const unsigned short* Kh = Kb  + (size_t)bh * SEQ * HD;
    const unsigned short* Vh = Vtb + (size_t)bh * HD * SEQ;

    // ---- per-lane staging source offsets (loop-invariant) ----
    int rS[2], cS[2];
    #pragma unroll
    for (int i = 0; i < 2; ++i) {
        int rp = w * 8 + 4 * i + (lane >> 4);
        int lc = (lane & 15) ^ (rp & 15);
        rS[i] = 2 * rp + (lc >> 3);
        cS[i] = lc & 7;
    }
    const int dst0 = (w * 8 + 0) * 128, dst1 = (w * 8 + 4) * 128;  // shorts
    const size_t kG0 = (size_t)rS[0] * HD  + cS[0] * 8;
    const size_t kG1 = (size_t)rS[1] * HD  + cS[1] * 8;
    const size_t vG0 = (size_t)rS[0] * SEQ + cS[0] * 8;
    const size_t vG1 = (size_t)rS[1] * SEQ + cS[1] * 8;

    // ---- prologue: tile 0 -> buf0 (async); Q (fp32 -> scaled bf16) -> QS ----
    {
        unsigned short* K0 = (unsigned short*)(SH);
        unsigned short* V0 = (unsigned short*)(SH + 8192);
        async_cp16(Kh + kG0, &K0[dst0]);
        async_cp16(Kh + kG1, &K0[dst1]);
        async_cp16(Vh + vG0, &V0[dst0]);
        async_cp16(Vh + vG1, &V0[dst1]);
    }
    #pragma unroll
    for (int u = 0; u < 4; ++u) {
        int idx = u * 1024 + tid * 4;
        int r = idx >> 6, col = idx & 63;
        float4 a = *(const float4*)&Qh[idx];
        uint2 pk = { pack2bf(a.x * qs, a.y * qs), pack2bf(a.z * qs, a.w * qs) };
        *(uint2*)&QS[tile_off(r, col >> 3) + (col & 7)] = pk;
    }
    __syncthreads();   // Q staged + tile 0 resident (full drain; prologue only)

    // ---- Q B-fragments (rows mt*32..+32) -> registers; then QS is free ----
    bf16x8 qf[4];
    #pragma unroll
    for (int s = 0; s < 4; ++s)
        qf[s] = *(const bf16x8*)&QS[tile_off(mt * 32 + l31, s * 2 + hi)];
    __syncthreads();   // everyone extracted Q; buf2 may be overwritten later

    // ---- tile 1 -> buf1 (stays in flight across the loop's first barrier) ----
    {
        unsigned short* K1 = (unsigned short*)(SH + 16384);
        unsigned short* V1 = (unsigned short*)(SH + 16384 + 8192);
        async_cp16(Kh + (size_t)TK * HD + kG0, &K1[dst0]);
        async_cp16(Kh + (size_t)TK * HD + kG1, &K1[dst1]);
        async_cp16(Vh + (size_t)TK + vG0,      &V1[dst0]);
        async_cp16(Vh + (size_t)TK + vG1,      &V1[dst1]);
    }

    // ---- hoisted fragment LDS offsets ----
    int kOffL[4], vOffL[2][2];
    #pragma unroll
    for (int s = 0; s < 4; ++s) kOffL[s] = tile_off(nt * 32 + l31, s * 2 + hi);
    #pragma unroll
    for (int dt = 0; dt < 2; ++dt)
        #pragma unroll
        for (int ks = 0; ks < 2; ++ks)
            vOffL[dt][ks] = tile_off(dt * 32 + l31, nt * 4 + ks * 2 + hi);

    f32x16 o[2];
    o[0] = (f32x16)(0.f);
    o[1] = (f32x16)(0.f);
    float lsum = 0.f;

    // deferred finish of a tile: exp2 + pack + PV + lsum (all register-local)
    auto FIN = [&](const f32x16& sp, const bf16x8 (&vp)[2][2]) {
        float e0[8], e1[8];
        #pragma unroll
        for (int r = 0; r < 8; ++r) e0[r] = EXP2F(sp[r]);
        #pragma unroll
        for (int r = 0; r < 8; ++r) e1[r] = EXP2F(sp[8 + r]);
        union { u32x4 d; bf16x8 h; } pu0, pu1;
        pu0.d = (u32x4){ pack2bf(e0[0], e0[1]), pack2bf(e0[2], e0[3]),
                         pack2bf(e0[4], e0[5]), pack2bf(e0[6], e0[7]) };
        pu1.d = (u32x4){ pack2bf(e1[0], e1[1]), pack2bf(e1[2], e1[3]),
                         pack2bf(e1[4], e1[5]), pack2bf(e1[6], e1[7]) };
        bf16x8 pf0 = pu0.h, pf1 = pu1.h;
        o[0] = __builtin_amdgcn_mfma_f32_32x32x16_bf16(pf0, vp[0][0], o[0], 0, 0, 0);
        o[1] = __builtin_amdgcn_mfma_f32_32x32x16_bf16(pf0, vp[1][0], o[1], 0, 0, 0);
        o[0] = __builtin_amdgcn_mfma_f32_32x32x16_bf16(pf1, vp[0][1], o[0], 0, 0, 0);
        o[1] = __builtin_amdgcn_mfma_f32_32x32x16_bf16(pf1, vp[1][1], o[1], 0, 0, 0);
        float t0 = ((e0[0] + e0[1]) + (e0[2] + e0[3]))
                 + ((e0[4] + e0[5]) + (e0[6] + e0[7]));
        float t1 = ((e1[0] + e1[1]) + (e1[2] + e1[3]))
                 + ((e1[4] + e1[5]) + (e1[6] + e1[7]));
        lsum += t0 + t1;
    };

    unsigned int b0 = 0, b1 = 16384, b2 = 32768;   // rotating buffer byte offsets

    // pipeline state: scores + V fragments of the previous tile
    f32x16 scp;
    bf16x8 vfp[2][2];

    // ---- peeled iteration 0: tile 0 resident, all waves synced (prologue) ----
    {
        // prefetch tile 2 into buf2 (overwrites QS — qf already extracted)
        unsigned short* Kn = (unsigned short*)(SH + b2);
        unsigned short* Vn = (unsigned short*)(SH + b2 + 8192);
        async_cp16(Kh + (size_t)2 * TK * HD + kG0, &Kn[dst0]);
        async_cp16(Kh + (size_t)2 * TK * HD + kG1, &Kn[dst1]);
        async_cp16(Vh + (size_t)2 * TK + vG0,      &Vn[dst0]);
        async_cp16(Vh + (size_t)2 * TK + vG1,      &Vn[dst1]);

        const unsigned short* Ks = (const unsigned short*)(SH + b0);
        const unsigned short* Vs = (const unsigned short*)(SH + b0 + 8192);
        #pragma unroll
        for (int dt = 0; dt < 2; ++dt)
            #pragma unroll
            for (int ks = 0; ks < 2; ++ks)
                vfp[dt][ks] = *(const bf16x8*)&Vs[vOffL[dt][ks]];
        f32x16 sc = (f32x16)(0.f);
        #pragma unroll
        for (int s = 0; s < 4; ++s) {
            bf16x8 kf = *(const bf16x8*)&Ks[kOffL[s]];
            sc = __builtin_amdgcn_mfma_f32_32x32x16_bf16(kf, qf[s], sc, 0, 0, 0);
        }
        scp = sc;
        unsigned int btmp = b0; b0 = b1; b1 = b2; b2 = btmp;
    }

    // ---- main loop: iter t = {ds_reads(t) -> FIN(t-1) in their shadow -> QK(t)}
    #pragma unroll 2
    for (int it = 1; it < NIT; ++it) {
        // all my ds_reads (incl. deferred V frags) complete before the barrier,
        // so the post-barrier prefetch into buf[(it+2)%3] cannot race them.
        asm volatile("s_waitcnt lgkmcnt(0)" ::: "memory");
        if (it == NIT - 1) { asm volatile("s_waitcnt vmcnt(0)" ::: "memory"); }
        else               { asm volatile("s_waitcnt vmcnt(4)" ::: "memory"); }
        __builtin_amdgcn_s_barrier();   // all waves: tile it resident

        const unsigned short* Ks = (const unsigned short*)(SH + b0);
        const unsigned short* Vs = (const unsigned short*)(SH + b0 + 8192);

        // ---- issue ALL fragment ds_reads for tile it up front ----
        bf16x8 kfc[4];
        #pragma unroll
        for (int s = 0; s < 4; ++s)
            kfc[s] = *(const bf16x8*)&Ks[kOffL[s]];
        bf16x8 vfc[2][2];
        #pragma unroll
        for (int dt = 0; dt < 2; ++dt)
            #pragma unroll
            for (int ks = 0; ks < 2; ++ks)
                vfc[dt][ks] = *(const bf16x8*)&Vs[vOffL[dt][ks]];

        if (it + 2 < NIT) {            // prefetch tile it+2 into rotating buffer
            const size_t kv = (size_t)(it + 2) * TK;
            unsigned short* Kn = (unsigned short*)(SH + b2);
            unsigned short* Vn = (unsigned short*)(SH + b2 + 8192);
            async_cp16(Kh + kv * HD + kG0, &Kn[dst0]);
            async_cp16(Kh + kv * HD + kG1, &Kn[dst1]);
            async_cp16(Vh + kv + vG0,      &Vn[dst0]);
            async_cp16(Vh + kv + vG1,      &Vn[dst1]);
        }

        // ---- FIN(it-1): register-only, runs in the ds_read latency shadow ----
        FIN(scp, vfp);

        // ---- QK MFMAs for tile it on the pre-read fragments ----
        f32x16 scc = (f32x16)(0.f);
        #pragma unroll
        for (int s = 0; s < 4; ++s)
            scc = __builtin_amdgcn_mfma_f32_32x32x16_bf16(kfc[s], qf[s], scc, 0, 0, 0);

        scp = scc;
        #pragma unroll
        for (int dt = 0; dt < 2; ++dt)
            #pragma unroll
            for (int ks = 0; ks < 2; ++ks)
                vfp[dt][ks] = vfc[dt][ks];

        unsigned int btmp = b0; b0 = b1; b1 = b2; b2 = btmp;
    }

    // ---- tail: finish the last tile ----
    FIN(scp, vfp);

    // ---- epilogue: combine nt partials (O and lsum), normalize, store ----
    // ORed overlays buf0; last iter's reads/prefetches touch buf1 only.
    lsum += __shfl_xor(lsum, 32, 64);

    if (nt == 1) {
        if (lane < 32) Lsum[mt * 32 + lane] = lsum;
        #pragma unroll
        for (int dt = 0; dt < 2; ++dt) {
            const int d = dt * 32 + l31;
            #pragma unroll
            for (int g = 0; g < 4; ++g) {
                const int m0 = mt * 32 + 8 * g + 4 * hi;
                const int ph = (m0 >> 2) ^ (d & 15);
                float4 v = { o[dt][4*g+0], o[dt][4*g+1], o[dt][4*g+2], o[dt][4*g+3] };
                *(float4*)&ORed[d * 64 + ph * 4] = v;
            }
        }
    }
    __syncthreads();

    if (nt == 0) {
        float ltot = lsum + Lsum[mt * 32 + l31];
        if (lane < 32) Linv[mt * 32 + lane] = 1.0f / ltot;
        float* Oh = O + ((size_t)bh * SEQ + q0) * HD;
        #pragma unroll
        for (int dt = 0; dt < 2; ++dt) {
            const int d = dt * 32 + l31;
            #pragma unroll
            for (int g = 0; g < 4; ++g) {
                const int m0 = mt * 32 + 8 * g + 4 * hi;
                const int ph = (m0 >> 2) ^ (d & 15);
                float4 part = *(const float4*)&ORed[d * 64 + ph * 4];
                float4 inv4 = *(const float4*)&Linv[m0];
                const float* pp = (const float*)&part;
                const float* ii = (const float*)&inv4;
                #pragma unroll
                for (int j = 0; j < 4; ++j)
                    Oh[(size_t)(m0 + j) * HD + d] = (o[dt][4*g+j] + pp[j]) * ii[j];
            }
        }
    }
}

// ---------------- fallback (no-workspace) kernel ----------------
#define PAD 8
#define LSTR (HD + PAD)

__global__ __launch_bounds__(256)
void fa_fwd_fb(const float* __restrict__ Q, const float* __restrict__ K,
               const float* __restrict__ V, float* __restrict__ O) {
    const int x  = blockIdx.x & 7;
    const int t  = blockIdx.x >> 3;
    const int bh = x + 8 * (t % 3);
    const int qt = t / 3;
    const int q0 = qt * TQ;
    const long base = (long)bh * SEQ * HD;

    __shared__ unsigned short Qs[TQ][LSTR];
    __shared__ unsigned short Ks2[64][LSTR];
    __shared__ unsigned short Vt[HD][64 + PAD];
    __shared__ unsigned short Ps2[4][16][LSTR];

    const int tid  = threadIdx.x;
    const int wave = tid >> 6;
    const int lane = tid & 63;
    const int col  = lane & 15;
    const int quad = lane >> 4;
    const int m0   = wave * 16;

    #pragma unroll
    for (int i = 0; i < 4; ++i) {
        int idx = tid + 256 * i;
        int row = idx >> 4;
        int c4  = (idx & 15) * 4;
        float4 v = *(const float4*)&Q[base + (long)(q0 + row) * HD + c4];
        ushort4 b = { f2bf(v.x), f2bf(v.y), f2bf(v.z), f2bf(v.w) };
        *(ushort4*)&Qs[row][c4] = b;
    }
    __syncthreads();

    bf16x8 aq0 = *(const bf16x8*)&Qs[m0 + col][quad * 8];
    bf16x8 aq1 = *(const bf16x8*)&Qs[m0 + col][32 + quad * 8];

    f32x4 o0 = {0.f,0.f,0.f,0.f}, o1 = o0, o2 = o0, o3 = o0;
    float l[4] = {0.f, 0.f, 0.f, 0.f};
    const float scale = 0.022097086912079608f;

    for (int kv0 = 0; kv0 < SEQ; kv0 += 64) {
        __syncthreads();
        #pragma unroll
        for (int i = 0; i < 4; ++i) {
            int idx = tid + 256 * i;
            int row = idx >> 4;
            int c4  = (idx & 15) * 4;
            float4 kv = *(const float4*)&K[base + (long)(kv0 + row) * HD + c4];
            ushort4 kb = { f2bf(kv.x), f2bf(kv.y), f2bf(kv.z), f2bf(kv.w) };
            *(ushort4*)&Ks2[row][c4] = kb;
            float4 vv = *(const float4*)&V[base + (long)(kv0 + row) * HD + c4];
            Vt[c4 + 0][row] = f2bf(vv.x);
            Vt[c4 + 1][row] = f2bf(vv.y);
            Vt[c4 + 2][row] = f2bf(vv.z);
            Vt[c4 + 3][row] = f2bf(vv.w);
        }
        __syncthreads();

        f32x4 sc[4];
        #pragma unroll
        for (int n = 0; n < 4; ++n) {
            bf16x8 b0 = *(const bf16x8*)&Ks2[n * 16 + col][quad * 8];
            bf16x8 b1 = *(const bf16x8*)&Ks2[n * 16 + col][32 + quad * 8];
            f32x4 acc = {0.f,0.f,0.f,0.f};
            acc = __builtin_amdgcn_mfma_f32_16x16x32_bf16(aq0, b0, acc, 0, 0, 0);
            acc = __builtin_amdgcn_mfma_f32_16x16x32_bf16(aq1, b1, acc, 0, 0, 0);
            sc[n] = acc;
        }

        float tsum[4] = {0.f, 0.f, 0.f, 0.f};
        #pragma unroll
        for (int n = 0; n < 4; ++n) {
            #pragma unroll
            for (int r = 0; r < 4; ++r) {
                float p = __expf(sc[n][r] * scale);
                tsum[r] += p;
                Ps2[wave][quad * 4 + r][n * 16 + col] = f2bf(p);
            }
        }
        #pragma unroll
        for (int off = 1; off < 16; off <<= 1) {
            #pragma unroll
            for (int r = 0; r < 4; ++r) tsum[r] += __shfl_xor(tsum[r], off, 64);
        }
        #pragma unroll
        for (int r = 0; r < 4; ++r) l[r] += tsum[r];

        bf16x8 ap0 = *(const bf16x8*)&Ps2[wave][col][quad * 8];
        bf16x8 ap1 = *(const bf16x8*)&Ps2[wave][col][32 + quad * 8];
        #pragma unroll
        for (int n = 0; n < 4; ++n) {
            bf16x8 b0 = *(const bf16x8*)&Vt[n * 16 + col][quad * 8];
            bf16x8 b1 = *(const bf16x8*)&Vt[n * 16 + col][32 + quad * 8];
            f32x4* op = (n == 0) ? &o0 : (n == 1) ? &o1 : (n == 2) ? &o2 : &o3;
            *op = __builtin_amdgcn_mfma_f32_16x16x32_bf16(ap0, b0, *op, 0, 0, 0);
            *op = __builtin_amdgcn_mfma_f32_16x16x32_bf16(ap1, b1, *op, 0, 0, 0);
        }
    }

    float inv[4];
    #pragma unroll
    for (int r = 0; r < 4; ++r) inv[r] = 1.0f / l[r];
    #pragma unroll
    for (int r = 0; r < 4; ++r) {
        long row = base + (long)(q0 + m0 + quad * 4 + r) * HD;
        O[row +  0 + col] = o0[r] * inv[r];
        O[row + 16 + col] = o1[r] * inv[r];
        O[row + 32 + col] = o2[r] * inv[r];
        O[row + 48 + col] = o3[r] * inv[r];
    }
}

extern "C" void kernel_launch(void* const* d_in, const int* in_sizes, int n_in,
                              void* d_out, int out_size, void* d_ws, size_t ws_size,
                              hipStream_t stream) {
    const float* Q = (const float*)d_in[0];
    const float* K = (const float*)d_in[1];
    const float* V = (const float*)d_in[2];
    float* O = (float*)d_out;

    const size_t tensorElems = (size_t)NHEADS * SEQ * HD;
    const size_t need = 2 * tensorElems * sizeof(unsigned short);

    if (ws_size >= need) {
        unsigned short* Kb  = (unsigned short*)d_ws;
        unsigned short* Vtb = Kb + tensorElems;
        const float qs = (float)(1.4426950408889634 / sqrt(2048.0));  // log2e/sqrt(S)
        prep_kv<<<dim3(NHEADS * (SEQ / 64)), dim3(256), 0, stream>>>(K, V, Kb, Vtb);
        fa_main<<<dim3(NHEADS * (SEQ / TQ)), dim3(256), 0, stream>>>(Q, Kb, Vtb, O, qs);
    } else {
        fa_fwd_fb<<<dim3(NHEADS * (SEQ / TQ)), dim3(256), 0, stream>>>(Q, K, V, O);
    }
}